// Round 4
// baseline (511.259 us; speedup 1.0000x reference)
//
#include <hip/hip_runtime.h>
#include <hip/hip_fp16.h>

// cosFormer linear attention, MI355X. L=S=2048, B=4, E=1024.
// R4: differential debug round. EXACT R1 source (passed, 443us) with ONE
// change: kv/attn GEMMs use a 128x64 tile (gemm_bt64, 1024 blocks = 4
// blocks/CU) instead of 128x128 (512 blocks = 2/CU). All R2/R3 fusions
// reverted to R1's separate kernels to isolate the NaN source.

typedef _Float16 f16;
typedef f16 f16x8 __attribute__((ext_vector_type(8)));
typedef f16 f16x4 __attribute__((ext_vector_type(4)));
typedef float f32x4 __attribute__((ext_vector_type(4)));

#define AS1 __attribute__((address_space(1)))
#define AS3 __attribute__((address_space(3)))

__device__ __forceinline__ void gload_lds16(const void* g, void* l) {
  // async global->LDS, 16B/lane; LDS dest = wave-uniform base + lane*16
  __builtin_amdgcn_global_load_lds((const AS1 void*)g, (AS3 void*)l, 16, 0, 0);
}

// ---------------------------------------------------------------------------
// f32 -> f16 convert (vectorized x4)
__global__ void cvt_f32_to_f16(const float* __restrict__ src, f16* __restrict__ dst, int n4) {
  const int i = blockIdx.x * 256 + threadIdx.x;
  if (i >= n4) return;
  const float4 v = ((const float4*)src)[i];
  f16x4 o = { (f16)v.x, (f16)v.y, (f16)v.z, (f16)v.w };
  ((f16x4*)dst)[i] = o;
}

// ---------------------------------------------------------------------------
// Generic 128x128x(BK=64) fp16 MFMA GEMM:  C[m][n] = sum_k A[m][k] * B[n][k]
// (R1-proven.) MODE 0: f16 C = acc + bias. MODE 1: Q/K proj dual write:
// relu(acc+bias)*sin at col n, *cos at col n+ldc/2.
template<int MODE>
__launch_bounds__(256)
__global__ void gemm_bt(const f16* __restrict__ A, int lda,
                        const f16* __restrict__ B, int ldb,
                        void* __restrict__ Cout, int K, int ldc,
                        const float* __restrict__ bias,
                        const float* __restrict__ zvec,
                        long abatch, long bbatch, long cbatch)
{
  __shared__ f16 As[16 * 512];   // 16 KB
  __shared__ f16 Bs[16 * 512];   // 16 KB
  const int tid  = threadIdx.x;
  const int lane = tid & 63;
  const int w    = tid >> 6;        // wave 0..3
  const int wm   = w >> 1, wn = w & 1;
  const int bz   = blockIdx.z;
  A += (long)bz * abatch;
  B += (long)bz * bbatch;
  const int m0   = blockIdx.y * 128;
  const int n0   = blockIdx.x * 128;
  const int l15  = lane & 15;
  const int quad = lane >> 4;

  f32x4 acc[4][4] = {};

  const f16* ag[4];
  const f16* bg[4];
  f16* al[4];
  f16* bl[4];
#pragma unroll
  for (int i = 0; i < 4; ++i) {
    const int bid = w * 4 + i;
    const int mt = bid >> 1;
    const int kt = bid & 1;
    ag[i] = A + (long)(m0 + mt * 16 + l15) * lda + kt * 32 + quad * 8;
    bg[i] = B + (long)(n0 + mt * 16 + l15) * ldb + kt * 32 + quad * 8;
    al[i] = As + bid * 512;
    bl[i] = Bs + bid * 512;
  }

  for (int k0 = 0; k0 < K; k0 += 64) {
#pragma unroll
    for (int i = 0; i < 4; ++i) {
      gload_lds16(ag[i], al[i]);
      gload_lds16(bg[i], bl[i]);
    }
#pragma unroll
    for (int i = 0; i < 4; ++i) { ag[i] += 64; bg[i] += 64; }
    __syncthreads();   // drains vmcnt -> LDS tiles ready
#pragma unroll
    for (int kt = 0; kt < 2; ++kt) {
      f16x8 af[4], bf[4];
#pragma unroll
      for (int i = 0; i < 4; ++i)
        af[i] = *(const f16x8*)(As + ((wm * 4 + i) * 2 + kt) * 512 + lane * 8);
#pragma unroll
      for (int j = 0; j < 4; ++j)
        bf[j] = *(const f16x8*)(Bs + ((wn * 4 + j) * 2 + kt) * 512 + lane * 8);
#pragma unroll
      for (int i = 0; i < 4; ++i)
#pragma unroll
        for (int j = 0; j < 4; ++j)
          acc[i][j] = __builtin_amdgcn_mfma_f32_16x16x32_f16(af[i], bf[j], acc[i][j], 0, 0, 0);
    }
    __syncthreads();   // all waves done reading before next stage
  }

  // Epilogue. C/D layout (verified m89/m91): col = lane&15, row = quad*4 + reg.
  if constexpr (MODE == 0) {
    f16* C = (f16*)Cout + (long)bz * cbatch;
#pragma unroll
    for (int i = 0; i < 4; ++i) {
      const int mg = m0 + wm * 64 + i * 16 + quad * 4;
#pragma unroll
      for (int j = 0; j < 4; ++j) {
        const int ng = n0 + wn * 64 + j * 16 + l15;
        const float bc = bias[ng];
#pragma unroll
        for (int rr = 0; rr < 4; ++rr)
          C[(long)(mg + rr) * ldc + ng] = (f16)(acc[i][j][rr] + bc);
      }
    }
  } else {  // MODE 1
    f16* C = (f16*)Cout;
    const int halfw = ldc >> 1;
#pragma unroll
    for (int i = 0; i < 4; ++i) {
      const int mg = m0 + wm * 64 + i * 16 + quad * 4;
      float sn[4], cn[4];
#pragma unroll
      for (int rr = 0; rr < 4; ++rr) {
        const int l = (mg + rr) >> 2;          // natural row = l*4 + b
        const float ang = 7.6699039394282066e-4f * (float)(l + 1);  // (pi/2)/2048 * (l+1)
        __sincosf(ang, &sn[rr], &cn[rr]);
      }
#pragma unroll
      for (int j = 0; j < 4; ++j) {
        const int ng = n0 + wn * 64 + j * 16 + l15;
        const float bc = bias[ng];
#pragma unroll
        for (int rr = 0; rr < 4; ++rr) {
          const float v = fmaxf(acc[i][j][rr] + bc, 0.f);
          C[(long)(mg + rr) * ldc + ng]         = (f16)(v * sn[rr]);
          C[(long)(mg + rr) * ldc + ng + halfw] = (f16)(v * cn[rr]);
        }
      }
    }
  }
}

// ---------------------------------------------------------------------------
// 128(M)x64(N)xBK64 GEMM, same structure as gemm_bt but half-width N tile.
// 4 waves: (wm,wn) each owns 64x32. As: 16 blocks (16KB), Bs: 8 blocks (8KB).
// MODE 2: f16 C = acc.  MODE 3: f32 C = acc * zvec[mg*4+bz].
template<int MODE>
__launch_bounds__(256)
__global__ void gemm_bt64(const f16* __restrict__ A, int lda,
                          const f16* __restrict__ B, int ldb,
                          void* __restrict__ Cout, int K, int ldc,
                          const float* __restrict__ zvec,
                          long abatch, long bbatch, long cbatch)
{
  __shared__ f16 As[16 * 512];   // 16 KB
  __shared__ f16 Bs[8 * 512];    // 8 KB
  const int tid  = threadIdx.x;
  const int lane = tid & 63;
  const int w    = tid >> 6;
  const int wm   = w >> 1, wn = w & 1;
  const int bz   = blockIdx.z;
  A += (long)bz * abatch;
  B += (long)bz * bbatch;
  const int m0   = blockIdx.y * 128;
  const int n0   = blockIdx.x * 64;
  const int l15  = lane & 15;
  const int quad = lane >> 4;

  f32x4 acc[4][2] = {};

  const f16* ag[4]; f16* al[4];
  const f16* bg[2]; f16* bl[2];
#pragma unroll
  for (int i = 0; i < 4; ++i) {
    const int bid = w * 4 + i;           // A blocks 0..15 (8 m-tiles x 2 k-halves)
    ag[i] = A + (long)(m0 + (bid >> 1) * 16 + l15) * lda + (bid & 1) * 32 + quad * 8;
    al[i] = As + bid * 512;
  }
#pragma unroll
  for (int i = 0; i < 2; ++i) {
    const int bid = w * 2 + i;           // B blocks 0..7 (4 n-tiles x 2 k-halves)
    bg[i] = B + (long)(n0 + (bid >> 1) * 16 + l15) * ldb + (bid & 1) * 32 + quad * 8;
    bl[i] = Bs + bid * 512;
  }

  for (int k0 = 0; k0 < K; k0 += 64) {
#pragma unroll
    for (int i = 0; i < 4; ++i) gload_lds16(ag[i], al[i]);
#pragma unroll
    for (int i = 0; i < 2; ++i) gload_lds16(bg[i], bl[i]);
#pragma unroll
    for (int i = 0; i < 4; ++i) ag[i] += 64;
#pragma unroll
    for (int i = 0; i < 2; ++i) bg[i] += 64;
    __syncthreads();
#pragma unroll
    for (int kt = 0; kt < 2; ++kt) {
      f16x8 af[4], bf[2];
#pragma unroll
      for (int i = 0; i < 4; ++i)
        af[i] = *(const f16x8*)(As + ((wm * 4 + i) * 2 + kt) * 512 + lane * 8);
#pragma unroll
      for (int j = 0; j < 2; ++j)
        bf[j] = *(const f16x8*)(Bs + ((wn * 2 + j) * 2 + kt) * 512 + lane * 8);
#pragma unroll
      for (int i = 0; i < 4; ++i)
#pragma unroll
        for (int j = 0; j < 2; ++j)
          acc[i][j] = __builtin_amdgcn_mfma_f32_16x16x32_f16(af[i], bf[j], acc[i][j], 0, 0, 0);
    }
    __syncthreads();
  }

  if constexpr (MODE == 2) {
    f16* C = (f16*)Cout + (long)bz * cbatch;
#pragma unroll
    for (int i = 0; i < 4; ++i) {
      const int mg = m0 + wm * 64 + i * 16 + quad * 4;
#pragma unroll
      for (int j = 0; j < 2; ++j) {
        const int ng = n0 + wn * 32 + j * 16 + l15;
#pragma unroll
        for (int rr = 0; rr < 4; ++rr)
          C[(long)(mg + rr) * ldc + ng] = (f16)(acc[i][j][rr]);
      }
    }
  } else {  // MODE 3: f32 out, scale by z
    float* C = (float*)Cout + (long)bz * cbatch;
#pragma unroll
    for (int i = 0; i < 4; ++i) {
      const int mg = m0 + wm * 64 + i * 16 + quad * 4;
      float zr[4];
#pragma unroll
      for (int rr = 0; rr < 4; ++rr) zr[rr] = zvec[(long)(mg + rr) * 4 + bz];
#pragma unroll
      for (int j = 0; j < 2; ++j) {
        const int ng = n0 + wn * 32 + j * 16 + l15;
#pragma unroll
        for (int rr = 0; rr < 4; ++rr)
          C[(long)(mg + rr) * ldc + ng] = acc[i][j][rr] * zr[rr];
      }
    }
  }
}

// ---------------------------------------------------------------------------
// fp16 64x64 LDS-tiled transpose: out[c][r] = in[r][c], per-batch strides.
__global__ void transpose_f16(const f16* __restrict__ in, f16* __restrict__ out,
                              long in_batch, long out_batch, int ldin, int ldout) {
  __shared__ f16 tile[64 * 72];   // +8 halves pad (keeps 16B alignment: 144B stride)
  const int b = blockIdx.z;
  in  += (long)b * in_batch;
  out += (long)b * out_batch;
  const int r0 = blockIdx.y * 64;
  const int c0 = blockIdx.x * 64;
  const int t  = threadIdx.x;
  {
    const int r = t >> 2, cs = (t & 3) * 16;
    const f16* src = in + (long)(r0 + r) * ldin + c0 + cs;
    f16x8 v0 = *(const f16x8*)(src);
    f16x8 v1 = *(const f16x8*)(src + 8);
    *(f16x8*)(tile + r * 72 + cs)     = v0;
    *(f16x8*)(tile + r * 72 + cs + 8) = v1;
  }
  __syncthreads();
  {
    const int c = t >> 2, rs = (t & 3) * 16;
    alignas(16) f16 tmp[16];
#pragma unroll
    for (int j = 0; j < 16; ++j) tmp[j] = tile[(rs + j) * 72 + c];
    f16* dst = out + (long)(c0 + c) * ldout + r0 + rs;
    *(f16x8*)(dst)     = *(const f16x8*)(tmp);
    *(f16x8*)(dst + 8) = *(const f16x8*)(tmp + 8);
  }
}

// ---------------------------------------------------------------------------
// k_sum[b][d] = sum_s K_t[b][d][s]  (one block per row of 2048)
__global__ void ksum_kernel(const f16* __restrict__ Kt, float* __restrict__ ks) {
  const long row = blockIdx.x;
  const int t = threadIdx.x;
  f16x8 v = *(const f16x8*)(Kt + row * 2048 + t * 8);
  float s = 0.f;
#pragma unroll
  for (int j = 0; j < 8; ++j) s += (float)v[j];
#pragma unroll
  for (int off = 32; off > 0; off >>= 1) s += __shfl_down(s, off, 64);
  __shared__ float red[4];
  if ((t & 63) == 0) red[t >> 6] = s;
  __syncthreads();
  if (t == 0) ks[row] = red[0] + red[1] + red[2] + red[3];
}

// z[r=l*4+b] = 1 / max(sum_d Q_[r][d] * k_sum[b][d], eps)
__global__ void z_kernel(const f16* __restrict__ Qf, const float* __restrict__ ks,
                         float* __restrict__ zb) {
  const long r = blockIdx.x;
  const int t = threadIdx.x;
  const int b = (int)(r & 3);
  f16x8 q = *(const f16x8*)(Qf + r * 2048 + t * 8);
  const float* kp = ks + b * 2048 + t * 8;
  float s = 0.f;
#pragma unroll
  for (int j = 0; j < 8; ++j) s += (float)q[j] * kp[j];
#pragma unroll
  for (int off = 32; off > 0; off >>= 1) s += __shfl_down(s, off, 64);
  __shared__ float red[4];
  if ((t & 63) == 0) red[t >> 6] = s;
  __syncthreads();
  if (t == 0) zb[r] = 1.f / fmaxf(red[0] + red[1] + red[2] + red[3], 1e-6f);
}

// ---------------------------------------------------------------------------
extern "C" void kernel_launch(void* const* d_in, const int* in_sizes, int n_in,
                              void* d_out, int out_size, void* d_ws, size_t ws_size,
                              hipStream_t stream) {
  const float* query = (const float*)d_in[0];
  const float* key_  = (const float*)d_in[1];
  const float* value = (const float*)d_in[2];
  const float* Wq    = (const float*)d_in[3];
  const float* bq    = (const float*)d_in[4];
  const float* Wk    = (const float*)d_in[5];
  const float* bk    = (const float*)d_in[6];
  const float* Wv    = (const float*)d_in[7];
  const float* bv    = (const float*)d_in[8];

  char* ws = (char*)d_ws;
  const size_t MB = 1ull << 20;
  // Workspace layout (peak 134 MB, with lifetime-based aliasing):
  f16* wq16 = (f16*)(ws + 0 * MB);    // 2 MB
  f16* wk16 = (f16*)(ws + 2 * MB);    // 2 MB
  f16* wv16 = (f16*)(ws + 4 * MB);    // 2 MB
  f16* q16  = (f16*)(ws + 6 * MB);    // 16 MB (dead after proj GEMMs)
  f16* k16  = (f16*)(ws + 22 * MB);   // 16 MB (dead after proj GEMMs)
  f16* v16  = (f16*)(ws + 38 * MB);   // 16 MB (dead after proj GEMMs)
  f16* Qf   = (f16*)(ws + 54 * MB);   // 32 MB  Q_ [l*4+b][2048]
  f16* Kn   = (f16*)(ws + 86 * MB);   // 32 MB  K_ natural [s*4+b][2048] (dead after transpose)
  f16* Vp   = (f16*)(ws + 118 * MB);  // 16 MB  V  natural [s*4+b][1024] (dead after transpose)
  f16* Kt   = (f16*)(ws + 6 * MB);    // 32 MB  K_t [b][d][s]   (aliases q16+k16)
  f16* Vt   = (f16*)(ws + 38 * MB);   // 16 MB  V_t [b][m][s]   (aliases v16)
  f16* kvb  = (f16*)(ws + 86 * MB);   // 16 MB  kv  [b][m][d]   (aliases Kn)
  float* ks = (float*)(ws + 102 * MB);  // 32 KB k_sum[b][d]
  float* zb = (float*)(ws + 103 * MB);  // 32 KB z[l*4+b]

  // 1) f32 -> f16
  cvt_f32_to_f16<<<8192, 256, 0, stream>>>(query, q16, 2097152);
  cvt_f32_to_f16<<<8192, 256, 0, stream>>>(key_,  k16, 2097152);
  cvt_f32_to_f16<<<8192, 256, 0, stream>>>(value, v16, 2097152);
  cvt_f32_to_f16<<<1024, 256, 0, stream>>>(Wq, wq16, 262144);
  cvt_f32_to_f16<<<1024, 256, 0, stream>>>(Wk, wk16, 262144);
  cvt_f32_to_f16<<<1024, 256, 0, stream>>>(Wv, wv16, 262144);

  // 2) projections (M=8192, N=1024, K=1024)
  gemm_bt<1><<<dim3(8, 64, 1), 256, 0, stream>>>(q16, 1024, wq16, 1024, Qf, 1024, 2048, bq, nullptr, 0, 0, 0);
  gemm_bt<1><<<dim3(8, 64, 1), 256, 0, stream>>>(k16, 1024, wk16, 1024, Kn, 1024, 2048, bk, nullptr, 0, 0, 0);
  gemm_bt<0><<<dim3(8, 64, 1), 256, 0, stream>>>(v16, 1024, wv16, 1024, Vp, 1024, 1024, bv, nullptr, 0, 0, 0);

  // 3) transposes: K_ [s][d] -> K_t [d][s]; V [s][m] -> V_t [m][s]  (per batch)
  transpose_f16<<<dim3(32, 32, 4), 256, 0, stream>>>(Kn, Kt, 2048, 2048L * 2048, 8192, 2048);
  transpose_f16<<<dim3(16, 32, 4), 256, 0, stream>>>(Vp, Vt, 1024, 1024L * 2048, 4096, 2048);

  // 4) k_sum and z
  ksum_kernel<<<8192, 256, 0, stream>>>(Kt, ks);
  z_kernel<<<8192, 256, 0, stream>>>(Qf, ks, zb);

  // 5) kv[b][m][d] = sum_s V_t[m][s] * K_t[d][s]   (M=1024, N=2048, K=2048)
  gemm_bt64<2><<<dim3(32, 8, 4), 256, 0, stream>>>(Vt, 2048, Kt, 2048, kvb, 2048, 2048,
                                                   nullptr, 1024L * 2048, 2048L * 2048, 1024L * 2048);
  // 6) attn[l][b][m] = z * sum_d Q_[l][d] * kv[m][d]  (M=2048, N=1024, K=2048), f32 out
  gemm_bt64<3><<<dim3(16, 16, 4), 256, 0, stream>>>(Qf, 8192, kvb, 2048, d_out, 2048, 4096,
                                                    zb, 2048, 1024L * 2048, 1024);
}

// Round 5
// 472.621 us; speedup vs baseline: 1.0818x; 1.0818x over previous
//
#include <hip/hip_runtime.h>
#include <hip/hip_fp16.h>

// cosFormer linear attention, MI355X. L=S=2048, B=4, E=1024.
// R5: R1 structure (proven correct, 443us) with ONE change: BK=64 -> BK=128
// in the GEMM (As/Bs 32KB each, 64KB LDS/block, still 2 blocks/CU at grid
// 512). Halves the number of per-K-step vmcnt drains (the measured
// bottleneck: R4 showed smaller tiles -> more drains -> slower), doubles
// MFMA per drain. All other kernels identical to R1.

typedef _Float16 f16;
typedef f16 f16x8 __attribute__((ext_vector_type(8)));
typedef f16 f16x4 __attribute__((ext_vector_type(4)));
typedef float f32x4 __attribute__((ext_vector_type(4)));

#define AS1 __attribute__((address_space(1)))
#define AS3 __attribute__((address_space(3)))

__device__ __forceinline__ void gload_lds16(const void* g, void* l) {
  // async global->LDS, 16B/lane; LDS dest = wave-uniform base + lane*16
  __builtin_amdgcn_global_load_lds((const AS1 void*)g, (AS3 void*)l, 16, 0, 0);
}

// ---------------------------------------------------------------------------
// f32 -> f16 convert (vectorized x4)
__global__ void cvt_f32_to_f16(const float* __restrict__ src, f16* __restrict__ dst, int n4) {
  const int i = blockIdx.x * 256 + threadIdx.x;
  if (i >= n4) return;
  const float4 v = ((const float4*)src)[i];
  f16x4 o = { (f16)v.x, (f16)v.y, (f16)v.z, (f16)v.w };
  ((f16x4*)dst)[i] = o;
}

// ---------------------------------------------------------------------------
// 128x128x(BK=128) fp16 MFMA GEMM:  C[m][n] = sum_k A[m][k] * B[n][k]
// Both operands k-contiguous. LDS: 32 fragment-blocks of 1KB per matrix;
// block(mt,kq) holds rows mt*16..+15, k kq*32..+31 in exact MFMA lane order
// (lane l's 16B at blockbase + l*16), so staging is global_load_lds w=16 and
// fragment loads are conflict-free ds_read_b128. K must be a multiple of 128.
// MODE 0: f16 C = acc + bias (V proj)
// MODE 1: f16 dual write: relu(acc+bias)*sin at col n, *cos at col n+ldc/2
// MODE 2: f16 C = acc (kv)
// MODE 3: f32 C = acc * zvec[mg*4+bz] (attn)
template<int MODE>
__launch_bounds__(256)
__global__ void gemm_bt(const f16* __restrict__ A, int lda,
                        const f16* __restrict__ B, int ldb,
                        void* __restrict__ Cout, int K, int ldc,
                        const float* __restrict__ bias,
                        const float* __restrict__ zvec,
                        long abatch, long bbatch, long cbatch)
{
  __shared__ f16 As[32 * 512];   // 32 KB
  __shared__ f16 Bs[32 * 512];   // 32 KB
  const int tid  = threadIdx.x;
  const int lane = tid & 63;
  const int w    = tid >> 6;        // wave 0..3
  const int wm   = w >> 1, wn = w & 1;
  const int bz   = blockIdx.z;
  A += (long)bz * abatch;
  B += (long)bz * bbatch;
  const int m0   = blockIdx.y * 128;
  const int n0   = blockIdx.x * 128;
  const int l15  = lane & 15;
  const int quad = lane >> 4;

  f32x4 acc[4][4] = {};

  // staging: 32 A-blocks + 32 B-blocks over 4 waves -> 8+8 per wave.
  // bid = w*8 + i; mt = bid>>2 (m-tile 0..7), kq = bid&3 (k-quarter 0..3).
  const f16* ag[8];
  const f16* bg[8];
  f16* al[8];
  f16* bl[8];
#pragma unroll
  for (int i = 0; i < 8; ++i) {
    const int bid = w * 8 + i;
    const int mt = bid >> 2;
    const int kq = bid & 3;
    ag[i] = A + (long)(m0 + mt * 16 + l15) * lda + kq * 32 + quad * 8;
    bg[i] = B + (long)(n0 + mt * 16 + l15) * ldb + kq * 32 + quad * 8;
    al[i] = As + bid * 512;
    bl[i] = Bs + bid * 512;
  }

  for (int k0 = 0; k0 < K; k0 += 128) {
#pragma unroll
    for (int i = 0; i < 8; ++i) {
      gload_lds16(ag[i], al[i]);
      gload_lds16(bg[i], bl[i]);
    }
#pragma unroll
    for (int i = 0; i < 8; ++i) { ag[i] += 128; bg[i] += 128; }
    __syncthreads();   // drains vmcnt -> LDS tiles ready
#pragma unroll
    for (int kt = 0; kt < 4; ++kt) {
      f16x8 af[4], bf[4];
#pragma unroll
      for (int i = 0; i < 4; ++i)
        af[i] = *(const f16x8*)(As + ((wm * 4 + i) * 4 + kt) * 512 + lane * 8);
#pragma unroll
      for (int j = 0; j < 4; ++j)
        bf[j] = *(const f16x8*)(Bs + ((wn * 4 + j) * 4 + kt) * 512 + lane * 8);
#pragma unroll
      for (int i = 0; i < 4; ++i)
#pragma unroll
        for (int j = 0; j < 4; ++j)
          acc[i][j] = __builtin_amdgcn_mfma_f32_16x16x32_f16(af[i], bf[j], acc[i][j], 0, 0, 0);
    }
    __syncthreads();   // all waves done reading before next stage
  }

  // Epilogue. C/D layout (verified m89/m91): col = lane&15, row = quad*4 + reg.
  if constexpr (MODE == 0 || MODE == 2) {
    f16* C = (f16*)Cout + (long)bz * cbatch;
#pragma unroll
    for (int i = 0; i < 4; ++i) {
      const int mg = m0 + wm * 64 + i * 16 + quad * 4;
#pragma unroll
      for (int j = 0; j < 4; ++j) {
        const int ng = n0 + wn * 64 + j * 16 + l15;
        const float bc = (MODE == 0) ? bias[ng] : 0.f;
#pragma unroll
        for (int rr = 0; rr < 4; ++rr)
          C[(long)(mg + rr) * ldc + ng] = (f16)(acc[i][j][rr] + bc);
      }
    }
  } else if constexpr (MODE == 1) {
    f16* C = (f16*)Cout;
    const int halfw = ldc >> 1;
#pragma unroll
    for (int i = 0; i < 4; ++i) {
      const int mg = m0 + wm * 64 + i * 16 + quad * 4;
      float sn[4], cn[4];
#pragma unroll
      for (int rr = 0; rr < 4; ++rr) {
        const int l = (mg + rr) >> 2;          // natural row = l*4 + b
        const float ang = 7.6699039394282066e-4f * (float)(l + 1);  // (pi/2)/2048 * (l+1)
        __sincosf(ang, &sn[rr], &cn[rr]);
      }
#pragma unroll
      for (int j = 0; j < 4; ++j) {
        const int ng = n0 + wn * 64 + j * 16 + l15;
        const float bc = bias[ng];
#pragma unroll
        for (int rr = 0; rr < 4; ++rr) {
          const float v = fmaxf(acc[i][j][rr] + bc, 0.f);
          C[(long)(mg + rr) * ldc + ng]         = (f16)(v * sn[rr]);
          C[(long)(mg + rr) * ldc + ng + halfw] = (f16)(v * cn[rr]);
        }
      }
    }
  } else {  // MODE 3: attn, f32 out, scale by z
    float* C = (float*)Cout + (long)bz * cbatch;
#pragma unroll
    for (int i = 0; i < 4; ++i) {
      const int mg = m0 + wm * 64 + i * 16 + quad * 4;
      float zr[4];
#pragma unroll
      for (int rr = 0; rr < 4; ++rr) zr[rr] = zvec[(long)(mg + rr) * 4 + bz];
#pragma unroll
      for (int j = 0; j < 4; ++j) {
        const int ng = n0 + wn * 64 + j * 16 + l15;
#pragma unroll
        for (int rr = 0; rr < 4; ++rr)
          C[(long)(mg + rr) * ldc + ng] = acc[i][j][rr] * zr[rr];
      }
    }
  }
}

// ---------------------------------------------------------------------------
// fp16 64x64 LDS-tiled transpose: out[c][r] = in[r][c], per-batch strides.
__global__ void transpose_f16(const f16* __restrict__ in, f16* __restrict__ out,
                              long in_batch, long out_batch, int ldin, int ldout) {
  __shared__ f16 tile[64 * 72];   // +8 halves pad (keeps 16B alignment: 144B stride)
  const int b = blockIdx.z;
  in  += (long)b * in_batch;
  out += (long)b * out_batch;
  const int r0 = blockIdx.y * 64;
  const int c0 = blockIdx.x * 64;
  const int t  = threadIdx.x;
  {
    const int r = t >> 2, cs = (t & 3) * 16;
    const f16* src = in + (long)(r0 + r) * ldin + c0 + cs;
    f16x8 v0 = *(const f16x8*)(src);
    f16x8 v1 = *(const f16x8*)(src + 8);
    *(f16x8*)(tile + r * 72 + cs)     = v0;
    *(f16x8*)(tile + r * 72 + cs + 8) = v1;
  }
  __syncthreads();
  {
    const int c = t >> 2, rs = (t & 3) * 16;
    alignas(16) f16 tmp[16];
#pragma unroll
    for (int j = 0; j < 16; ++j) tmp[j] = tile[(rs + j) * 72 + c];
    f16* dst = out + (long)(c0 + c) * ldout + r0 + rs;
    *(f16x8*)(dst)     = *(const f16x8*)(tmp);
    *(f16x8*)(dst + 8) = *(const f16x8*)(tmp + 8);
  }
}

// ---------------------------------------------------------------------------
// k_sum[b][d] = sum_s K_t[b][d][s]  (one block per row of 2048)
__global__ void ksum_kernel(const f16* __restrict__ Kt, float* __restrict__ ks) {
  const long row = blockIdx.x;
  const int t = threadIdx.x;
  f16x8 v = *(const f16x8*)(Kt + row * 2048 + t * 8);
  float s = 0.f;
#pragma unroll
  for (int j = 0; j < 8; ++j) s += (float)v[j];
#pragma unroll
  for (int off = 32; off > 0; off >>= 1) s += __shfl_down(s, off, 64);
  __shared__ float red[4];
  if ((t & 63) == 0) red[t >> 6] = s;
  __syncthreads();
  if (t == 0) ks[row] = red[0] + red[1] + red[2] + red[3];
}

// z[r=l*4+b] = 1 / max(sum_d Q_[r][d] * k_sum[b][d], eps)
__global__ void z_kernel(const f16* __restrict__ Qf, const float* __restrict__ ks,
                         float* __restrict__ zb) {
  const long r = blockIdx.x;
  const int t = threadIdx.x;
  const int b = (int)(r & 3);
  f16x8 q = *(const f16x8*)(Qf + r * 2048 + t * 8);
  const float* kp = ks + b * 2048 + t * 8;
  float s = 0.f;
#pragma unroll
  for (int j = 0; j < 8; ++j) s += (float)q[j] * kp[j];
#pragma unroll
  for (int off = 32; off > 0; off >>= 1) s += __shfl_down(s, off, 64);
  __shared__ float red[4];
  if ((t & 63) == 0) red[t >> 6] = s;
  __syncthreads();
  if (t == 0) zb[r] = 1.f / fmaxf(red[0] + red[1] + red[2] + red[3], 1e-6f);
}

// ---------------------------------------------------------------------------
extern "C" void kernel_launch(void* const* d_in, const int* in_sizes, int n_in,
                              void* d_out, int out_size, void* d_ws, size_t ws_size,
                              hipStream_t stream) {
  const float* query = (const float*)d_in[0];
  const float* key_  = (const float*)d_in[1];
  const float* value = (const float*)d_in[2];
  const float* Wq    = (const float*)d_in[3];
  const float* bq    = (const float*)d_in[4];
  const float* Wk    = (const float*)d_in[5];
  const float* bk    = (const float*)d_in[6];
  const float* Wv    = (const float*)d_in[7];
  const float* bv    = (const float*)d_in[8];

  char* ws = (char*)d_ws;
  const size_t MB = 1ull << 20;
  // Workspace layout (peak 134 MB, with lifetime-based aliasing):
  f16* wq16 = (f16*)(ws + 0 * MB);    // 2 MB
  f16* wk16 = (f16*)(ws + 2 * MB);    // 2 MB
  f16* wv16 = (f16*)(ws + 4 * MB);    // 2 MB
  f16* q16  = (f16*)(ws + 6 * MB);    // 16 MB (dead after proj GEMMs)
  f16* k16  = (f16*)(ws + 22 * MB);   // 16 MB (dead after proj GEMMs)
  f16* v16  = (f16*)(ws + 38 * MB);   // 16 MB (dead after proj GEMMs)
  f16* Qf   = (f16*)(ws + 54 * MB);   // 32 MB  Q_ [l*4+b][2048]
  f16* Kn   = (f16*)(ws + 86 * MB);   // 32 MB  K_ natural [s*4+b][2048] (dead after transpose)
  f16* Vp   = (f16*)(ws + 118 * MB);  // 16 MB  V  natural [s*4+b][1024] (dead after transpose)
  f16* Kt   = (f16*)(ws + 6 * MB);    // 32 MB  K_t [b][d][s]   (aliases q16+k16)
  f16* Vt   = (f16*)(ws + 38 * MB);   // 16 MB  V_t [b][m][s]   (aliases v16)
  f16* kvb  = (f16*)(ws + 86 * MB);   // 16 MB  kv  [b][m][d]   (aliases Kn)
  float* ks = (float*)(ws + 102 * MB);  // 32 KB k_sum[b][d]
  float* zb = (float*)(ws + 103 * MB);  // 32 KB z[l*4+b]

  // 1) f32 -> f16
  cvt_f32_to_f16<<<8192, 256, 0, stream>>>(query, q16, 2097152);
  cvt_f32_to_f16<<<8192, 256, 0, stream>>>(key_,  k16, 2097152);
  cvt_f32_to_f16<<<8192, 256, 0, stream>>>(value, v16, 2097152);
  cvt_f32_to_f16<<<1024, 256, 0, stream>>>(Wq, wq16, 262144);
  cvt_f32_to_f16<<<1024, 256, 0, stream>>>(Wk, wk16, 262144);
  cvt_f32_to_f16<<<1024, 256, 0, stream>>>(Wv, wv16, 262144);

  // 2) projections (M=8192, N=1024, K=1024)
  gemm_bt<1><<<dim3(8, 64, 1), 256, 0, stream>>>(q16, 1024, wq16, 1024, Qf, 1024, 2048, bq, nullptr, 0, 0, 0);
  gemm_bt<1><<<dim3(8, 64, 1), 256, 0, stream>>>(k16, 1024, wk16, 1024, Kn, 1024, 2048, bk, nullptr, 0, 0, 0);
  gemm_bt<0><<<dim3(8, 64, 1), 256, 0, stream>>>(v16, 1024, wv16, 1024, Vp, 1024, 1024, bv, nullptr, 0, 0, 0);

  // 3) transposes: K_ [s][d] -> K_t [d][s]; V [s][m] -> V_t [m][s]  (per batch)
  transpose_f16<<<dim3(32, 32, 4), 256, 0, stream>>>(Kn, Kt, 2048, 2048L * 2048, 8192, 2048);
  transpose_f16<<<dim3(16, 32, 4), 256, 0, stream>>>(Vp, Vt, 1024, 1024L * 2048, 4096, 2048);

  // 4) k_sum and z
  ksum_kernel<<<8192, 256, 0, stream>>>(Kt, ks);
  z_kernel<<<8192, 256, 0, stream>>>(Qf, ks, zb);

  // 5) kv[b][m][d] = sum_s V_t[m][s] * K_t[d][s]   (M=1024, N=2048, K=2048)
  gemm_bt<2><<<dim3(16, 8, 4), 256, 0, stream>>>(Vt, 2048, Kt, 2048, kvb, 2048, 2048,
                                                 nullptr, nullptr, 1024L * 2048, 2048L * 2048, 1024L * 2048);
  // 6) attn[l][b][m] = z * sum_d Q_[l][d] * kv[m][d]  (M=2048, N=1024, K=2048), f32 out
  gemm_bt<3><<<dim3(8, 16, 4), 256, 0, stream>>>(Qf, 8192, kvb, 2048, d_out, 2048, 4096,
                                                 nullptr, zb, 2048, 1024L * 2048, 1024);
}

// Round 6
// 470.691 us; speedup vs baseline: 1.0862x; 1.0041x over previous
//
#include <hip/hip_runtime.h>
#include <hip/hip_fp16.h>

// cosFormer linear attention, MI355X. L=S=2048, B=4, E=1024.
// R6: base = R1 (best, 443us; BK=64 128x128 gemm proven).
// Changes: (1) attn GEMM split-K=2 -> 1024 blocks (4/CU, VGPR cap),
// f32 atomicAdd into zeroed d_out (z-scaling distributes over partials);
// (2) 6 cvt dispatches -> 1 (simple grid-(x,job) mapping);
// (3) 3 proj dispatches -> 1 (proj3; controlled NaN-suspect retest —
// transpose_ks / kvz fusions from R2/R3 remain EXCLUDED).

typedef _Float16 f16;
typedef f16 f16x8 __attribute__((ext_vector_type(8)));
typedef f16 f16x4 __attribute__((ext_vector_type(4)));
typedef float f32x4 __attribute__((ext_vector_type(4)));

#define AS1 __attribute__((address_space(1)))
#define AS3 __attribute__((address_space(3)))

__device__ __forceinline__ void gload_lds16(const void* g, void* l) {
  // async global->LDS, 16B/lane; LDS dest = wave-uniform base + lane*16
  __builtin_amdgcn_global_load_lds((const AS1 void*)g, (AS3 void*)l, 16, 0, 0);
}

// ---------------------------------------------------------------------------
// All 6 f32->f16 converts, one dispatch. grid (8192, 6); job = blockIdx.y.
// Jobs 0-2: 2097152 float4 (q/k/v). Jobs 3-5: 262144 float4 (weights);
// excess blocks return.
struct CvtArgs { const float* src[6]; f16* dst[6]; int n4[6]; };

__global__ void cvt_all(CvtArgs a) {
  const int job = blockIdx.y;
  const int off = blockIdx.x * 256 + threadIdx.x;
  if (off >= a.n4[job]) return;
  const float4 v = ((const float4*)a.src[job])[off];
  f16x4 o = { (f16)v.x, (f16)v.y, (f16)v.z, (f16)v.w };
  ((f16x4*)a.dst[job])[off] = o;
}

// ---------------------------------------------------------------------------
// Merged projection GEMMs: 128x128xBK64, R1-proven body. grid (8,64,3).
// M=8192, N=1024, K=1024, lda=ldb=1024.
// mode 1 (Q/K): dual write relu(acc+bias)*{sin,cos} at col n / n+ldc/2.
// mode 0 (V):   f16 C = acc + bias.
struct ProjArgs {
  const f16* A[3]; const f16* Bm[3]; f16* C[3]; const float* bias[3];
  int ldc[3]; int mode[3];
};

__launch_bounds__(256)
__global__ void proj3_kernel(ProjArgs pa) {
  __shared__ f16 As[16 * 512];   // 16 KB
  __shared__ f16 Bs[16 * 512];   // 16 KB
  const int pz = blockIdx.z;
  const f16* A = pa.A[pz];
  const f16* B = pa.Bm[pz];
  f16* C = pa.C[pz];
  const float* bias = pa.bias[pz];
  const int ldc = pa.ldc[pz];
  const int mode = pa.mode[pz];
  const int lda = 1024, ldb = 1024, K = 1024;

  const int tid  = threadIdx.x;
  const int lane = tid & 63;
  const int w    = tid >> 6;
  const int wm   = w >> 1, wn = w & 1;
  const int m0   = blockIdx.y * 128;
  const int n0   = blockIdx.x * 128;
  const int l15  = lane & 15;
  const int quad = lane >> 4;

  f32x4 acc[4][4] = {};

  const f16* ag[4]; const f16* bg[4]; f16* al[4]; f16* bl[4];
#pragma unroll
  for (int i = 0; i < 4; ++i) {
    const int bid = w * 4 + i;
    const int mt = bid >> 1, kt = bid & 1;
    ag[i] = A + (long)(m0 + mt * 16 + l15) * lda + kt * 32 + quad * 8;
    bg[i] = B + (long)(n0 + mt * 16 + l15) * ldb + kt * 32 + quad * 8;
    al[i] = As + bid * 512;
    bl[i] = Bs + bid * 512;
  }

  for (int k0 = 0; k0 < K; k0 += 64) {
#pragma unroll
    for (int i = 0; i < 4; ++i) { gload_lds16(ag[i], al[i]); gload_lds16(bg[i], bl[i]); }
#pragma unroll
    for (int i = 0; i < 4; ++i) { ag[i] += 64; bg[i] += 64; }
    __syncthreads();
#pragma unroll
    for (int kt = 0; kt < 2; ++kt) {
      f16x8 af[4], bf[4];
#pragma unroll
      for (int i = 0; i < 4; ++i)
        af[i] = *(const f16x8*)(As + ((wm * 4 + i) * 2 + kt) * 512 + lane * 8);
#pragma unroll
      for (int j = 0; j < 4; ++j)
        bf[j] = *(const f16x8*)(Bs + ((wn * 4 + j) * 2 + kt) * 512 + lane * 8);
#pragma unroll
      for (int i = 0; i < 4; ++i)
#pragma unroll
        for (int j = 0; j < 4; ++j)
          acc[i][j] = __builtin_amdgcn_mfma_f32_16x16x32_f16(af[i], bf[j], acc[i][j], 0, 0, 0);
    }
    __syncthreads();
  }

  // C/D layout: col = lane&15, row = quad*4 + reg.
  if (mode == 1) {
    const int halfw = ldc >> 1;
#pragma unroll
    for (int i = 0; i < 4; ++i) {
      const int mg = m0 + wm * 64 + i * 16 + quad * 4;
      float sn[4], cn[4];
#pragma unroll
      for (int rr = 0; rr < 4; ++rr) {
        const int l = (mg + rr) >> 2;   // natural row = l*4 + b
        const float ang = 7.6699039394282066e-4f * (float)(l + 1);  // (pi/2)/2048*(l+1)
        __sincosf(ang, &sn[rr], &cn[rr]);
      }
#pragma unroll
      for (int j = 0; j < 4; ++j) {
        const int ng = n0 + wn * 64 + j * 16 + l15;
        const float bc = bias[ng];
#pragma unroll
        for (int rr = 0; rr < 4; ++rr) {
          const float v = fmaxf(acc[i][j][rr] + bc, 0.f);
          C[(long)(mg + rr) * ldc + ng]         = (f16)(v * sn[rr]);
          C[(long)(mg + rr) * ldc + ng + halfw] = (f16)(v * cn[rr]);
        }
      }
    }
  } else {
#pragma unroll
    for (int i = 0; i < 4; ++i) {
      const int mg = m0 + wm * 64 + i * 16 + quad * 4;
#pragma unroll
      for (int j = 0; j < 4; ++j) {
        const int ng = n0 + wn * 64 + j * 16 + l15;
        const float bc = bias[ng];
#pragma unroll
        for (int rr = 0; rr < 4; ++rr)
          C[(long)(mg + rr) * ldc + ng] = (f16)(acc[i][j][rr] + bc);
      }
    }
  }
}

// ---------------------------------------------------------------------------
// kv GEMM: R1-proven 128x128xBK64, MODE2 epilogue (f16 C = acc).
// grid (16,8,4): per batch kv[m][d] = sum_s Vt[m][s]*Kt[d][s].
__launch_bounds__(256)
__global__ void kv_kernel(const f16* __restrict__ Vt, const f16* __restrict__ Kt,
                          f16* __restrict__ kvb) {
  __shared__ f16 As[16 * 512];
  __shared__ f16 Bs[16 * 512];
  const int tid  = threadIdx.x;
  const int lane = tid & 63;
  const int w    = tid >> 6;
  const int wm   = w >> 1, wn = w & 1;
  const int bz   = blockIdx.z;
  const f16* A = Vt + (long)bz * 1024 * 2048;
  const f16* B = Kt + (long)bz * 2048 * 2048;
  const int lda = 2048, ldb = 2048, K = 2048, ldc = 2048;
  const int m0   = blockIdx.y * 128;
  const int n0   = blockIdx.x * 128;
  const int l15  = lane & 15;
  const int quad = lane >> 4;

  f32x4 acc[4][4] = {};

  const f16* ag[4]; const f16* bg[4]; f16* al[4]; f16* bl[4];
#pragma unroll
  for (int i = 0; i < 4; ++i) {
    const int bid = w * 4 + i;
    const int mt = bid >> 1, kt = bid & 1;
    ag[i] = A + (long)(m0 + mt * 16 + l15) * lda + kt * 32 + quad * 8;
    bg[i] = B + (long)(n0 + mt * 16 + l15) * ldb + kt * 32 + quad * 8;
    al[i] = As + bid * 512;
    bl[i] = Bs + bid * 512;
  }

  for (int k0 = 0; k0 < K; k0 += 64) {
#pragma unroll
    for (int i = 0; i < 4; ++i) { gload_lds16(ag[i], al[i]); gload_lds16(bg[i], bl[i]); }
#pragma unroll
    for (int i = 0; i < 4; ++i) { ag[i] += 64; bg[i] += 64; }
    __syncthreads();
#pragma unroll
    for (int kt = 0; kt < 2; ++kt) {
      f16x8 af[4], bf[4];
#pragma unroll
      for (int i = 0; i < 4; ++i)
        af[i] = *(const f16x8*)(As + ((wm * 4 + i) * 2 + kt) * 512 + lane * 8);
#pragma unroll
      for (int j = 0; j < 4; ++j)
        bf[j] = *(const f16x8*)(Bs + ((wn * 4 + j) * 2 + kt) * 512 + lane * 8);
#pragma unroll
      for (int i = 0; i < 4; ++i)
#pragma unroll
        for (int j = 0; j < 4; ++j)
          acc[i][j] = __builtin_amdgcn_mfma_f32_16x16x32_f16(af[i], bf[j], acc[i][j], 0, 0, 0);
    }
    __syncthreads();
  }

  f16* C = kvb + (long)bz * 1024 * 2048;
#pragma unroll
  for (int i = 0; i < 4; ++i) {
    const int mg = m0 + wm * 64 + i * 16 + quad * 4;
#pragma unroll
    for (int j = 0; j < 4; ++j) {
      const int ng = n0 + wn * 64 + j * 16 + l15;
#pragma unroll
      for (int rr = 0; rr < 4; ++rr)
        C[(long)(mg + rr) * ldc + ng] = (f16)(acc[i][j][rr]);
    }
  }
}

// ---------------------------------------------------------------------------
// attn GEMM, split-K=2: grid (8,16,8); z = bz*2 + kh. Each block computes a
// 128x128 tile over K-half 1024 (16 BK64 steps) and atomicAdds acc*z into
// the ZEROED f32 output. Same staging/compute body as R1.
__launch_bounds__(256)
__global__ void attn_kernel(const f16* __restrict__ Qf, const f16* __restrict__ kvb,
                            float* __restrict__ out, const float* __restrict__ zb) {
  __shared__ f16 As[16 * 512];
  __shared__ f16 Bs[16 * 512];
  const int tid  = threadIdx.x;
  const int lane = tid & 63;
  const int w    = tid >> 6;
  const int wm   = w >> 1, wn = w & 1;
  const int bz   = blockIdx.z >> 1;
  const int kh   = blockIdx.z & 1;
  // A: batch view of Qf (row l -> l*4+bz), k-offset kh*1024. lda = 8192.
  const f16* A = Qf + (long)bz * 2048 + (long)kh * 1024;
  const f16* B = kvb + (long)bz * 1024 * 2048 + (long)kh * 1024;
  const int lda = 8192, ldb = 2048, K = 1024, ldc = 4096;
  const int m0   = blockIdx.y * 128;
  const int n0   = blockIdx.x * 128;
  const int l15  = lane & 15;
  const int quad = lane >> 4;

  f32x4 acc[4][4] = {};

  const f16* ag[4]; const f16* bg[4]; f16* al[4]; f16* bl[4];
#pragma unroll
  for (int i = 0; i < 4; ++i) {
    const int bid = w * 4 + i;
    const int mt = bid >> 1, kt = bid & 1;
    ag[i] = A + (long)(m0 + mt * 16 + l15) * lda + kt * 32 + quad * 8;
    bg[i] = B + (long)(n0 + mt * 16 + l15) * ldb + kt * 32 + quad * 8;
    al[i] = As + bid * 512;
    bl[i] = Bs + bid * 512;
  }

  for (int k0 = 0; k0 < K; k0 += 64) {
#pragma unroll
    for (int i = 0; i < 4; ++i) { gload_lds16(ag[i], al[i]); gload_lds16(bg[i], bl[i]); }
#pragma unroll
    for (int i = 0; i < 4; ++i) { ag[i] += 64; bg[i] += 64; }
    __syncthreads();
#pragma unroll
    for (int kt = 0; kt < 2; ++kt) {
      f16x8 af[4], bf[4];
#pragma unroll
      for (int i = 0; i < 4; ++i)
        af[i] = *(const f16x8*)(As + ((wm * 4 + i) * 2 + kt) * 512 + lane * 8);
#pragma unroll
      for (int j = 0; j < 4; ++j)
        bf[j] = *(const f16x8*)(Bs + ((wn * 4 + j) * 2 + kt) * 512 + lane * 8);
#pragma unroll
      for (int i = 0; i < 4; ++i)
#pragma unroll
        for (int j = 0; j < 4; ++j)
          acc[i][j] = __builtin_amdgcn_mfma_f32_16x16x32_f16(af[i], bf[j], acc[i][j], 0, 0, 0);
    }
    __syncthreads();
  }

  float* C = out + (long)bz * 1024;
#pragma unroll
  for (int i = 0; i < 4; ++i) {
    const int mg = m0 + wm * 64 + i * 16 + quad * 4;
    float zr[4];
#pragma unroll
    for (int rr = 0; rr < 4; ++rr) zr[rr] = zb[(long)(mg + rr) * 4 + bz];
#pragma unroll
    for (int j = 0; j < 4; ++j) {
      const int ng = n0 + wn * 64 + j * 16 + l15;
#pragma unroll
      for (int rr = 0; rr < 4; ++rr)
        atomicAdd(&C[(long)(mg + rr) * ldc + ng], acc[i][j][rr] * zr[rr]);
    }
  }
}

// ---------------------------------------------------------------------------
// fp16 64x64 LDS-tiled transpose: out[c][r] = in[r][c], per-batch strides.
__global__ void transpose_f16(const f16* __restrict__ in, f16* __restrict__ out,
                              long in_batch, long out_batch, int ldin, int ldout) {
  __shared__ f16 tile[64 * 72];   // +8 halves pad (keeps 16B alignment: 144B stride)
  const int b = blockIdx.z;
  in  += (long)b * in_batch;
  out += (long)b * out_batch;
  const int r0 = blockIdx.y * 64;
  const int c0 = blockIdx.x * 64;
  const int t  = threadIdx.x;
  {
    const int r = t >> 2, cs = (t & 3) * 16;
    const f16* src = in + (long)(r0 + r) * ldin + c0 + cs;
    f16x8 v0 = *(const f16x8*)(src);
    f16x8 v1 = *(const f16x8*)(src + 8);
    *(f16x8*)(tile + r * 72 + cs)     = v0;
    *(f16x8*)(tile + r * 72 + cs + 8) = v1;
  }
  __syncthreads();
  {
    const int c = t >> 2, rs = (t & 3) * 16;
    alignas(16) f16 tmp[16];
#pragma unroll
    for (int j = 0; j < 16; ++j) tmp[j] = tile[(rs + j) * 72 + c];
    f16* dst = out + (long)(c0 + c) * ldout + r0 + rs;
    *(f16x8*)(dst)     = *(const f16x8*)(tmp);
    *(f16x8*)(dst + 8) = *(const f16x8*)(tmp + 8);
  }
}

// ---------------------------------------------------------------------------
// k_sum[b][d] = sum_s K_t[b][d][s]  (one block per row of 2048)
__global__ void ksum_kernel(const f16* __restrict__ Kt, float* __restrict__ ks) {
  const long row = blockIdx.x;
  const int t = threadIdx.x;
  f16x8 v = *(const f16x8*)(Kt + row * 2048 + t * 8);
  float s = 0.f;
#pragma unroll
  for (int j = 0; j < 8; ++j) s += (float)v[j];
#pragma unroll
  for (int off = 32; off > 0; off >>= 1) s += __shfl_down(s, off, 64);
  __shared__ float red[4];
  if ((t & 63) == 0) red[t >> 6] = s;
  __syncthreads();
  if (t == 0) ks[row] = red[0] + red[1] + red[2] + red[3];
}

// z[r=l*4+b] = 1 / max(sum_d Q_[r][d] * k_sum[b][d], eps)
__global__ void z_kernel(const f16* __restrict__ Qf, const float* __restrict__ ks,
                         float* __restrict__ zb) {
  const long r = blockIdx.x;
  const int t = threadIdx.x;
  const int b = (int)(r & 3);
  f16x8 q = *(const f16x8*)(Qf + r * 2048 + t * 8);
  const float* kp = ks + b * 2048 + t * 8;
  float s = 0.f;
#pragma unroll
  for (int j = 0; j < 8; ++j) s += (float)q[j] * kp[j];
#pragma unroll
  for (int off = 32; off > 0; off >>= 1) s += __shfl_down(s, off, 64);
  __shared__ float red[4];
  if ((t & 63) == 0) red[t >> 6] = s;
  __syncthreads();
  if (t == 0) zb[r] = 1.f / fmaxf(red[0] + red[1] + red[2] + red[3], 1e-6f);
}

// ---------------------------------------------------------------------------
extern "C" void kernel_launch(void* const* d_in, const int* in_sizes, int n_in,
                              void* d_out, int out_size, void* d_ws, size_t ws_size,
                              hipStream_t stream) {
  const float* query = (const float*)d_in[0];
  const float* key_  = (const float*)d_in[1];
  const float* value = (const float*)d_in[2];
  const float* Wq    = (const float*)d_in[3];
  const float* bq    = (const float*)d_in[4];
  const float* Wk    = (const float*)d_in[5];
  const float* bk    = (const float*)d_in[6];
  const float* Wv    = (const float*)d_in[7];
  const float* bv    = (const float*)d_in[8];

  char* ws = (char*)d_ws;
  const size_t MB = 1ull << 20;
  // Workspace layout (peak 134 MB, lifetime-based aliasing):
  f16* wq16 = (f16*)(ws + 0 * MB);
  f16* wk16 = (f16*)(ws + 2 * MB);
  f16* wv16 = (f16*)(ws + 4 * MB);
  f16* q16  = (f16*)(ws + 6 * MB);
  f16* k16  = (f16*)(ws + 22 * MB);
  f16* v16  = (f16*)(ws + 38 * MB);
  f16* Qf   = (f16*)(ws + 54 * MB);   // Q_ [l*4+b][2048]
  f16* Kn   = (f16*)(ws + 86 * MB);   // K_ natural [s*4+b][2048]
  f16* Vp   = (f16*)(ws + 118 * MB);  // V  natural [s*4+b][1024]
  f16* Kt   = (f16*)(ws + 6 * MB);    // K_t [b][d][s] (aliases q16+k16)
  f16* Vt   = (f16*)(ws + 38 * MB);   // V_t [b][m][s] (aliases v16)
  f16* kvb  = (f16*)(ws + 86 * MB);   // kv  [b][m][d] (aliases Kn)
  float* ks = (float*)(ws + 102 * MB);
  float* zb = (float*)(ws + 103 * MB);

  // zero the f32 output (attn accumulates via atomicAdd, split-K=2)
  hipMemsetAsync(d_out, 0, (size_t)out_size * sizeof(float), stream);

  // 1) f32 -> f16 (single dispatch)
  CvtArgs ca;
  ca.src[0] = query; ca.src[1] = key_; ca.src[2] = value;
  ca.src[3] = Wq; ca.src[4] = Wk; ca.src[5] = Wv;
  ca.dst[0] = q16; ca.dst[1] = k16; ca.dst[2] = v16;
  ca.dst[3] = wq16; ca.dst[4] = wk16; ca.dst[5] = wv16;
  ca.n4[0] = ca.n4[1] = ca.n4[2] = 2097152;
  ca.n4[3] = ca.n4[4] = ca.n4[5] = 262144;
  cvt_all<<<dim3(8192, 6, 1), 256, 0, stream>>>(ca);

  // 2) projections (single dispatch, 1536 blocks)
  ProjArgs pa;
  pa.A[0] = q16;  pa.A[1] = k16;  pa.A[2] = v16;
  pa.Bm[0] = wq16; pa.Bm[1] = wk16; pa.Bm[2] = wv16;
  pa.C[0] = Qf;   pa.C[1] = Kn;   pa.C[2] = Vp;
  pa.bias[0] = bq; pa.bias[1] = bk; pa.bias[2] = bv;
  pa.ldc[0] = 2048; pa.ldc[1] = 2048; pa.ldc[2] = 1024;
  pa.mode[0] = 1; pa.mode[1] = 1; pa.mode[2] = 0;
  proj3_kernel<<<dim3(8, 64, 3), 256, 0, stream>>>(pa);

  // 3) transposes
  transpose_f16<<<dim3(32, 32, 4), 256, 0, stream>>>(Kn, Kt, 2048, 2048L * 2048, 8192, 2048);
  transpose_f16<<<dim3(16, 32, 4), 256, 0, stream>>>(Vp, Vt, 1024, 1024L * 2048, 4096, 2048);

  // 4) k_sum and z
  ksum_kernel<<<8192, 256, 0, stream>>>(Kt, ks);
  z_kernel<<<8192, 256, 0, stream>>>(Qf, ks, zb);

  // 5) kv[b][m][d] = sum_s V_t[m][s] * K_t[d][s]
  kv_kernel<<<dim3(16, 8, 4), 256, 0, stream>>>(Vt, Kt, kvb);

  // 6) attn, split-K=2, atomic f32 accumulate
  attn_kernel<<<dim3(8, 16, 8), 256, 0, stream>>>(Qf, kvb, (float*)d_out, zb);
}